// Round 2
// baseline (808.775 us; speedup 1.0000x reference)
//
#include <hip/hip_runtime.h>
#include <hip/hip_bf16.h>
#include <math.h>
#include <stdint.h>

// Fused FeedForwardQuantum, round 2:
//   prep kernel: W2 -> bf16 [n][k] XOR-swizzled linear tile images in ws (4.7MB),
//                g[m] = cos(x[m,0:4])*cos(theta) (256KB), W1T[k][4] (48KB)
//   main kernel: 64x128 output tile, 4 waves, BK=64, grid 1536 (6 blocks/CU),
//                B staged via async global_load_lds (linear dest, pre-swizzled src),
//                A (=h tile) generated in-register from g/W1T -> swizzled ds_write.

typedef __bf16 bf16_t;
typedef __attribute__((ext_vector_type(8))) __bf16 bf16x8;
typedef __attribute__((ext_vector_type(4))) float f32x4;

#define M_TOT 16384
#define E_DIM 768
#define F_DIM 3072

constexpr int BM = 64, BN = 128, BK = 64;
constexpr int MT = M_TOT / BM;    // 256
constexpr int NT = E_DIM / BN;    // 6
constexpr int KT = F_DIM / BK;    // 48

// ws layout (bytes)
constexpr size_t WS_B   = 0;                                   // NT*KT tiles * 16KB = 4,718,592
constexpr size_t WS_G   = WS_B + (size_t)NT * KT * 16384;      // 16384 * 16B float4
constexpr size_t WS_W1T = WS_G + (size_t)M_TOT * 16;           // 3072 * 16B float4

// ---------------------------------------------------------------- prep ----
__global__ __launch_bounds__(256)
void ffq_prep(const float* __restrict__ x, const float* __restrict__ theta,
              const float* __restrict__ W1, const float* __restrict__ W2,
              char* __restrict__ ws)
{
    const int t = threadIdx.x;
    const int bid = blockIdx.x;
    if (bid < KT * NT) {
        // W2 tile (kt,nt): 64k x 128n f32 -> bf16 swizzled linear image (16KB)
        const int kt = bid / NT, nt = bid % NT;
        __shared__ float Wf[64][132];   // padded: conflict-light column reads
        const int r  = t >> 5;          // 0..7
        const int c4 = (t & 31) << 2;   // 0..124
        #pragma unroll
        for (int i = 0; i < 8; ++i) {
            const int row = i * 8 + r;
            const float4 v = *reinterpret_cast<const float4*>(
                &W2[(size_t)(kt * 64 + row) * E_DIM + nt * 128 + c4]);
            Wf[row][c4] = v.x; Wf[row][c4 + 1] = v.y;
            Wf[row][c4 + 2] = v.z; Wf[row][c4 + 3] = v.w;
        }
        __syncthreads();
        char* dst = ws + WS_B + (size_t)(nt * KT + kt) * 16384;
        #pragma unroll
        for (int c = 0; c < 4; ++c) {
            const int b16 = c * 256 + t;          // 16B-chunk index 0..1023
            const int n = b16 >> 3, os = b16 & 7; // stored octet slot
            const int ko = os ^ (n & 7);          // logical k-octet
            bf16x8 v;
            #pragma unroll
            for (int j = 0; j < 8; ++j) v[j] = (bf16_t)Wf[ko * 8 + j][n];
            *reinterpret_cast<bf16x8*>(dst + (size_t)b16 * 16) = v;
        }
    } else if (bid < KT * NT + M_TOT / 256) {
        // g rows
        const int m = (bid - KT * NT) * 256 + t;
        const float4 xv = *reinterpret_cast<const float4*>(x + (size_t)m * E_DIM);
        float4 g;
        g.x = cosf(xv.x) * cosf(theta[0]);
        g.y = cosf(xv.y) * cosf(theta[1]);
        g.z = cosf(xv.z) * cosf(theta[2]);
        g.w = cosf(xv.w) * cosf(theta[3]);
        *reinterpret_cast<float4*>(ws + WS_G + (size_t)m * 16) = g;
    } else {
        // W1 transpose: W1T[k] = {W1[0][k],W1[1][k],W1[2][k],W1[3][k]}
        const int k = (bid - KT * NT - M_TOT / 256) * 256 + t;
        float4 w;
        w.x = W1[k];
        w.y = W1[F_DIM + k];
        w.z = W1[2 * F_DIM + k];
        w.w = W1[3 * F_DIM + k];
        *reinterpret_cast<float4*>(ws + WS_W1T + (size_t)k * 16) = w;
    }
}

// ---------------------------------------------------------------- main ----
__global__ __launch_bounds__(256, 4)
void ffq_main(const char* __restrict__ ws, const float* __restrict__ b1,
              const float* __restrict__ b2, float* __restrict__ out)
{
    __shared__ bf16_t Asm[BM][BK];   // 8KB  h tile, [m][k] octet-swizzled
    __shared__ bf16_t Bsm[BN][BK];   // 16KB W2 tile, linear image (pre-swizzled)
    __shared__ float4 gsm[BM];       // 1KB

    const int t = threadIdx.x;
    const int lane = t & 63, wid = t >> 6;

    // XCD swizzle: 1536 % 8 == 0; chunks of 192 stay within <=2 n-slabs
    const int bid = blockIdx.x;
    const int swz = (bid & 7) * (MT * NT / 8) + (bid >> 3);
    const int nt = swz / MT, mt = swz % MT;
    const int m0 = mt * BM, n0 = nt * BN;

    if (t < BM)
        gsm[t] = *reinterpret_cast<const float4*>(ws + WS_G + (size_t)(m0 + t) * 16);
    __syncthreads();

    // A-gen roles
    const int row = t >> 2;          // 0..63
    const int kq  = t & 3;           // k-quarter: octets 2kq, 2kq+1
    // mfma roles
    const int wr = wid >> 1, wc = wid & 1;
    const int fr = lane & 15, fg = lane >> 4;

    const char* srcB = ws + WS_B + (size_t)nt * KT * 16384;
    const float4* w1t = reinterpret_cast<const float4*>(ws + WS_W1T);

    const float4 g = gsm[row];

    f32x4 acc[2][4] = {};

    for (int kt = 0; kt < KT; ++kt) {
        // ---- B: async global->LDS, 16KB linear, 4 rounds x (4 waves x 1KB) ----
        {
            const char* srct = srcB + (size_t)kt * 16384;
            #pragma unroll
            for (int r = 0; r < 4; ++r) {
                const int off = r * 4096 + wid * 1024 + lane * 16;
                __builtin_amdgcn_global_load_lds(
                    (const __attribute__((address_space(1))) void*)(srct + off),
                    (__attribute__((address_space(3))) void*)((char*)&Bsm[0][0] + r * 4096 + wid * 1024),
                    16, 0, 0);
            }
        }
        // ---- A-gen: 16 h-values (one row, 16 consecutive k) per thread ----
        {
            const int kbase = kt * 64 + kq * 16;
            const float4* wp = w1t + kbase;
            const float*  bp = b1 + kbase;
            #pragma unroll
            for (int h = 0; h < 2; ++h) {
                bf16x8 v;
                #pragma unroll
                for (int j = 0; j < 8; ++j) {
                    const int kk = h * 8 + j;
                    const float4 w = wp[kk];
                    float p = bp[kk];
                    p = fmaf(g.x, w.x, p);
                    p = fmaf(g.y, w.y, p);
                    p = fmaf(g.z, w.z, p);
                    p = fmaf(g.w, w.w, p);
                    v[j] = (bf16_t)fmaxf(p, 0.0f);
                }
                const int oc = kq * 2 + h;
                *reinterpret_cast<bf16x8*>(&Asm[row][(oc ^ (row & 7)) * 8]) = v;
            }
        }
        __syncthreads();   // drains vmcnt (B in LDS) + lgkm (A writes)

        // ---- MFMA: 2 k-slices of 32 ----
        #pragma unroll
        for (int ks = 0; ks < 2; ++ks) {
            const int kob = ks * 4 + fg;
            bf16x8 af[2], bfr[4];
            #pragma unroll
            for (int mi = 0; mi < 2; ++mi) {
                const int ra = wr * 32 + mi * 16 + fr;
                af[mi] = *reinterpret_cast<const bf16x8*>(&Asm[ra][(kob ^ (ra & 7)) * 8]);
            }
            #pragma unroll
            for (int ni = 0; ni < 4; ++ni) {
                const int rb = wc * 64 + ni * 16 + fr;
                bfr[ni] = *reinterpret_cast<const bf16x8*>(&Bsm[rb][(kob ^ (rb & 7)) * 8]);
            }
            #pragma unroll
            for (int mi = 0; mi < 2; ++mi)
                #pragma unroll
                for (int ni = 0; ni < 4; ++ni)
                    acc[mi][ni] = __builtin_amdgcn_mfma_f32_16x16x32_bf16(
                        af[mi], bfr[ni], acc[mi][ni], 0, 0, 0);
        }
        __syncthreads();
    }

    // ---- epilogue (C/D: col=lane&15, row=(lane>>4)*4+r) ----
    #pragma unroll
    for (int ni = 0; ni < 4; ++ni) {
        const int col = n0 + wc * 64 + ni * 16 + fr;
        const float bias = b2[col];
        #pragma unroll
        for (int mi = 0; mi < 2; ++mi) {
            #pragma unroll
            for (int rr = 0; rr < 4; ++rr) {
                const int ro = m0 + wr * 32 + mi * 16 + fg * 4 + rr;
                out[(size_t)ro * E_DIM + col] = acc[mi][ni][rr] + bias;
            }
        }
    }
}

extern "C" void kernel_launch(void* const* d_in, const int* in_sizes, int n_in,
                              void* d_out, int out_size, void* d_ws, size_t ws_size,
                              hipStream_t stream) {
    const float* x     = (const float*)d_in[0];
    const float* theta = (const float*)d_in[1];
    const float* W1    = (const float*)d_in[2];
    const float* b1    = (const float*)d_in[3];
    const float* W2    = (const float*)d_in[4];
    const float* b2    = (const float*)d_in[5];
    float* out = (float*)d_out;

    const int prep_blocks = KT * NT + M_TOT / 256 + F_DIM / 256;   // 288+64+12
    hipLaunchKernelGGL(ffq_prep, dim3(prep_blocks), dim3(256), 0, stream,
                       x, theta, W1, W2, (char*)d_ws);
    hipLaunchKernelGGL(ffq_main, dim3(MT * NT), dim3(256), 0, stream,
                       (const char*)d_ws, b1, b2, out);
}

// Round 3
// 164.993 us; speedup vs baseline: 4.9019x; 4.9019x over previous
//
#include <hip/hip_runtime.h>
#include <hip/hip_bf16.h>
#include <math.h>
#include <stdint.h>

// Round 3: split into prep (h materialized as bf16 swizzled tile-images in ws)
// + m97-structure GEMM. Fallback to round-1 fused kernel if ws too small.

typedef __bf16 bf16_t;
typedef __attribute__((ext_vector_type(8))) __bf16 bf16x8;
typedef __attribute__((ext_vector_type(4))) float f32x4;

#define M_TOT 16384
#define E_DIM 768
#define F_DIM 3072

constexpr int BM = 128, BN = 128, BK = 64;
constexpr int MT = M_TOT / BM;    // 128
constexpr int NT = E_DIM / BN;    // 6
constexpr int KT = F_DIM / BK;    // 48
constexpr int TILE_B = 16384;     // bytes per 128x64 bf16 tile image

// ws layout
constexpr size_t WS_A    = 0;                                    // MT*KT tiles
constexpr size_t WS_B    = WS_A + (size_t)MT * KT * TILE_B;      // NT*KT tiles
constexpr size_t WS_NEED = WS_B + (size_t)NT * KT * TILE_B;      // ~100.5 MiB

// ------------------------------------------------------------ prep: W2 ----
__global__ __launch_bounds__(256)
void ffq_prep_w2t(const float* __restrict__ W2, char* __restrict__ ws)
{
    const int t = threadIdx.x;
    const int kt = blockIdx.x / NT, nt = blockIdx.x % NT;
    __shared__ float Wf[64][132];
    const int r  = t >> 5;
    const int c4 = (t & 31) << 2;
    #pragma unroll
    for (int i = 0; i < 8; ++i) {
        const int row = i * 8 + r;
        const float4 v = *reinterpret_cast<const float4*>(
            &W2[(size_t)(kt * 64 + row) * E_DIM + nt * 128 + c4]);
        Wf[row][c4] = v.x; Wf[row][c4 + 1] = v.y;
        Wf[row][c4 + 2] = v.z; Wf[row][c4 + 3] = v.w;
    }
    __syncthreads();
    char* dst = ws + WS_B + (size_t)(nt * KT + kt) * TILE_B;
    #pragma unroll
    for (int c = 0; c < 4; ++c) {
        const int b16 = c * 256 + t;          // chunk 0..1023
        const int n = b16 >> 3, os = b16 & 7; // stored octet slot
        const int ko = os ^ (n & 7);          // logical k-octet
        bf16x8 v;
        #pragma unroll
        for (int j = 0; j < 8; ++j) v[j] = (bf16_t)Wf[ko * 8 + j][n];
        *reinterpret_cast<bf16x8*>(dst + (size_t)b16 * 16) = v;
    }
}

// ------------------------------------------------------------- prep: h ----
// block = (mt, kt). thread t: row = t&127, half = t>>7 (32 k each).
// h[m][k] = relu(sum_q cos(x[m][q])cos(theta[q]) * W1[q][k] + b1[k]) as bf16,
// stored octet-XOR swizzled into Hsm then linearly to the tile image.
__global__ __launch_bounds__(256)
void ffq_prep_h(const float* __restrict__ x, const float* __restrict__ theta,
                const float* __restrict__ W1, const float* __restrict__ b1,
                char* __restrict__ ws)
{
    __shared__ bf16_t Hsm[BM][BK];
    const int t = threadIdx.x;
    const int mt = blockIdx.x / KT, kt = blockIdx.x % KT;
    const int row = t & 127, half = t >> 7;
    const int m = mt * BM + row;
    const int kb = kt * 64 + half * 32;

    const float4 xv = *reinterpret_cast<const float4*>(x + (size_t)m * E_DIM);
    const float gx = cosf(xv.x) * cosf(theta[0]);
    const float gy = cosf(xv.y) * cosf(theta[1]);
    const float gz = cosf(xv.z) * cosf(theta[2]);
    const float gw = cosf(xv.w) * cosf(theta[3]);

    #pragma unroll
    for (int o = 0; o < 4; ++o) {            // 4 octets of 8 k
        const int k0 = kb + o * 8;
        bf16x8 v;
        #pragma unroll
        for (int j = 0; j < 8; ++j) {
            const int k = k0 + j;
            float p = b1[k];
            p = fmaf(gx, W1[k],              p);
            p = fmaf(gy, W1[F_DIM + k],      p);
            p = fmaf(gz, W1[2 * F_DIM + k],  p);
            p = fmaf(gw, W1[3 * F_DIM + k],  p);
            v[j] = (bf16_t)fmaxf(p, 0.0f);
        }
        const int oc = half * 4 + o;         // logical octet 0..7
        *reinterpret_cast<bf16x8*>(&Hsm[row][(oc ^ (row & 7)) * 8]) = v;
    }
    __syncthreads();
    char* dst = ws + WS_A + (size_t)(mt * KT + kt) * TILE_B;
    const char* srcl = (const char*)&Hsm[0][0];
    #pragma unroll
    for (int r = 0; r < 4; ++r) {
        const int c = r * 256 + t;           // linear chunk copy
        *reinterpret_cast<bf16x8*>(dst + (size_t)c * 16) =
            *reinterpret_cast<const bf16x8*>(srcl + (size_t)c * 16);
    }
}

// ---------------------------------------------------------------- GEMM ----
__global__ __launch_bounds__(256)
void ffq_gemm(const char* __restrict__ ws, const float* __restrict__ b2,
              float* __restrict__ out)
{
    __shared__ bf16_t Asm[BM][BK];   // 16KB, swizzled image (linear copy)
    __shared__ bf16_t Bsm[BN][BK];   // 16KB

    const int t = threadIdx.x;
    const int lane = t & 63, wid = t >> 6;

    const int bid = blockIdx.x;                       // 768 = 8*96
    const int swz = (bid & 7) * (MT * NT / 8) + (bid >> 3);
    const int nt = swz / MT, mt = swz % MT;
    const int m0 = mt * BM, n0 = nt * BN;

    const char* srcA = ws + WS_A + (size_t)mt * KT * TILE_B;
    const char* srcB = ws + WS_B + (size_t)nt * KT * TILE_B;

    const int wr = wid >> 1, wc = wid & 1;
    const int fr = lane & 15, fg = lane >> 4;

    f32x4 acc[4][4] = {};

    for (int kt = 0; kt < KT; ++kt) {
        const char* sa = srcA + (size_t)kt * TILE_B;
        const char* sb = srcB + (size_t)kt * TILE_B;
        #pragma unroll
        for (int r = 0; r < 4; ++r) {
            const int off = r * 4096 + wid * 1024 + lane * 16;
            __builtin_amdgcn_global_load_lds(
                (const __attribute__((address_space(1))) void*)(sa + off),
                (__attribute__((address_space(3))) void*)((char*)&Asm[0][0] + r * 4096 + wid * 1024),
                16, 0, 0);
        }
        #pragma unroll
        for (int r = 0; r < 4; ++r) {
            const int off = r * 4096 + wid * 1024 + lane * 16;
            __builtin_amdgcn_global_load_lds(
                (const __attribute__((address_space(1))) void*)(sb + off),
                (__attribute__((address_space(3))) void*)((char*)&Bsm[0][0] + r * 4096 + wid * 1024),
                16, 0, 0);
        }
        __syncthreads();

        #pragma unroll
        for (int ks = 0; ks < 2; ++ks) {
            const int kob = ks * 4 + fg;
            bf16x8 af[4], bfr[4];
            #pragma unroll
            for (int mi = 0; mi < 4; ++mi) {
                const int ra = wr * 64 + mi * 16 + fr;
                af[mi] = *reinterpret_cast<const bf16x8*>(&Asm[ra][(kob ^ (ra & 7)) * 8]);
            }
            #pragma unroll
            for (int ni = 0; ni < 4; ++ni) {
                const int rb = wc * 64 + ni * 16 + fr;
                bfr[ni] = *reinterpret_cast<const bf16x8*>(&Bsm[rb][(kob ^ (rb & 7)) * 8]);
            }
            #pragma unroll
            for (int mi = 0; mi < 4; ++mi)
                #pragma unroll
                for (int ni = 0; ni < 4; ++ni)
                    acc[mi][ni] = __builtin_amdgcn_mfma_f32_16x16x32_bf16(
                        af[mi], bfr[ni], acc[mi][ni], 0, 0, 0);
        }
        __syncthreads();
    }

    #pragma unroll
    for (int ni = 0; ni < 4; ++ni) {
        const int col = n0 + wc * 64 + ni * 16 + fr;
        const float bias = b2[col];
        #pragma unroll
        for (int mi = 0; mi < 4; ++mi) {
            #pragma unroll
            for (int rr = 0; rr < 4; ++rr) {
                const int ro = m0 + wr * 64 + mi * 16 + fg * 4 + rr;
                out[(size_t)ro * E_DIM + col] = acc[mi][ni][rr] + bias;
            }
        }
    }
}

// ------------------------------------------- fallback: round-1 fused ------
__global__ __launch_bounds__(256, 2)
void ffq_fused(const float* __restrict__ x, const float* __restrict__ theta,
               const float* __restrict__ W1, const float* __restrict__ b1,
               const float* __restrict__ W2, const float* __restrict__ b2,
               float* __restrict__ out)
{
    __shared__ bf16_t Asm[BM][BK];
    __shared__ bf16_t Bsm[BN][BK];
    __shared__ float  gsm[BM][4];
    __shared__ float  b2sm[BN];

    const int t = threadIdx.x;
    const int lane = t & 63, wid = t >> 6;
    const int bid = blockIdx.x;
    const int swz = (bid & 7) * (MT * NT / 8) + (bid >> 3);
    const int ntile = swz / MT, mtile = swz % MT;
    const int m0 = mtile * BM, n0 = ntile * BN;

    const float c0 = cosf(theta[0]), c1 = cosf(theta[1]);
    const float c2 = cosf(theta[2]), c3 = cosf(theta[3]);
    if (t < BM) {
        const float4 xv = *reinterpret_cast<const float4*>(x + (size_t)(m0 + t) * E_DIM);
        gsm[t][0] = cosf(xv.x) * c0; gsm[t][1] = cosf(xv.y) * c1;
        gsm[t][2] = cosf(xv.z) * c2; gsm[t][3] = cosf(xv.w) * c3;
    } else {
        const int n = t - 128;
        b2sm[n] = b2[n0 + n];
    }
    __syncthreads();

    const int rg = t >> 3, kg = t & 7;
    const int nB = t & 127, kh = t >> 7;
    const int wr = wid >> 1, wc = wid & 1;
    const int fr = lane & 15, fg = lane >> 4;

    f32x4 acc[4][4] = {};

    for (int k0 = 0; k0 < F_DIM; k0 += BK) {
        {
            const int kA = k0 + (kg << 3);
            float w1v[4][8], b1v[8];
            #pragma unroll
            for (int q = 0; q < 4; ++q) {
                const float4 lo = *reinterpret_cast<const float4*>(&W1[q * F_DIM + kA]);
                const float4 hi = *reinterpret_cast<const float4*>(&W1[q * F_DIM + kA + 4]);
                w1v[q][0] = lo.x; w1v[q][1] = lo.y; w1v[q][2] = lo.z; w1v[q][3] = lo.w;
                w1v[q][4] = hi.x; w1v[q][5] = hi.y; w1v[q][6] = hi.z; w1v[q][7] = hi.w;
            }
            {
                const float4 lo = *reinterpret_cast<const float4*>(&b1[kA]);
                const float4 hi = *reinterpret_cast<const float4*>(&b1[kA + 4]);
                b1v[0] = lo.x; b1v[1] = lo.y; b1v[2] = lo.z; b1v[3] = lo.w;
                b1v[4] = hi.x; b1v[5] = hi.y; b1v[6] = hi.z; b1v[7] = hi.w;
            }
            #pragma unroll
            for (int r = 0; r < 4; ++r) {
                const int row = (rg << 2) + r;
                const float4 g = *reinterpret_cast<const float4*>(&gsm[row][0]);
                bf16x8 v;
                #pragma unroll
                for (int kk = 0; kk < 8; ++kk) {
                    float p = b1v[kk];
                    p = fmaf(g.x, w1v[0][kk], p);
                    p = fmaf(g.y, w1v[1][kk], p);
                    p = fmaf(g.z, w1v[2][kk], p);
                    p = fmaf(g.w, w1v[3][kk], p);
                    v[kk] = (bf16_t)fmaxf(p, 0.0f);
                }
                *reinterpret_cast<bf16x8*>(&Asm[row][(kg ^ (row & 7)) << 3]) = v;
            }
        }
        {
            const float* w2p = W2 + (size_t)(k0 + (kh << 5)) * E_DIM + n0 + nB;
            float bv[32];
            #pragma unroll
            for (int kk = 0; kk < 32; ++kk) bv[kk] = w2p[kk * E_DIM];
            #pragma unroll
            for (int o = 0; o < 4; ++o) {
                bf16x8 v;
                #pragma unroll
                for (int j = 0; j < 8; ++j) v[j] = (bf16_t)bv[(o << 3) + j];
                *reinterpret_cast<bf16x8*>(&Bsm[nB][(((kh << 2) + o) ^ (nB & 7)) << 3]) = v;
            }
        }
        __syncthreads();
        #pragma unroll
        for (int ks = 0; ks < 2; ++ks) {
            const int kob = (ks << 2) + fg;
            bf16x8 af[4], bfr[4];
            #pragma unroll
            for (int mi = 0; mi < 4; ++mi) {
                const int row = (wr << 6) + (mi << 4) + fr;
                af[mi] = *reinterpret_cast<const bf16x8*>(&Asm[row][(kob ^ (row & 7)) << 3]);
            }
            #pragma unroll
            for (int ni = 0; ni < 4; ++ni) {
                const int rn = (wc << 6) + (ni << 4) + fr;
                bfr[ni] = *reinterpret_cast<const bf16x8*>(&Bsm[rn][(kob ^ (rn & 7)) << 3]);
            }
            #pragma unroll
            for (int mi = 0; mi < 4; ++mi)
                #pragma unroll
                for (int ni = 0; ni < 4; ++ni)
                    acc[mi][ni] = __builtin_amdgcn_mfma_f32_16x16x32_bf16(
                        af[mi], bfr[ni], acc[mi][ni], 0, 0, 0);
        }
        __syncthreads();
    }

    #pragma unroll
    for (int mi = 0; mi < 4; ++mi)
        #pragma unroll
        for (int ni = 0; ni < 4; ++ni) {
            const int col  = n0 + (wc << 6) + (ni << 4) + fr;
            const float bias = b2sm[(wc << 6) + (ni << 4) + fr];
            #pragma unroll
            for (int r = 0; r < 4; ++r) {
                const int row = m0 + (wr << 6) + (mi << 4) + (fg << 2) + r;
                out[(size_t)row * E_DIM + col] = acc[mi][ni][r] + bias;
            }
        }
}

// -------------------------------------------------------------- launch ----
extern "C" void kernel_launch(void* const* d_in, const int* in_sizes, int n_in,
                              void* d_out, int out_size, void* d_ws, size_t ws_size,
                              hipStream_t stream) {
    const float* x     = (const float*)d_in[0];
    const float* theta = (const float*)d_in[1];
    const float* W1    = (const float*)d_in[2];
    const float* b1    = (const float*)d_in[3];
    const float* W2    = (const float*)d_in[4];
    const float* b2    = (const float*)d_in[5];
    float* out = (float*)d_out;

    if (ws_size >= WS_NEED) {
        hipLaunchKernelGGL(ffq_prep_w2t, dim3(KT * NT), dim3(256), 0, stream,
                           W2, (char*)d_ws);
        hipLaunchKernelGGL(ffq_prep_h, dim3(MT * KT), dim3(256), 0, stream,
                           x, theta, W1, b1, (char*)d_ws);
        hipLaunchKernelGGL(ffq_gemm, dim3(MT * NT), dim3(256), 0, stream,
                           (const char*)d_ws, b2, out);
    } else {
        hipLaunchKernelGGL(ffq_fused, dim3(MT * NT), dim3(256), 0, stream,
                           x, theta, W1, b1, W2, b2, out);
    }
}

// Round 4
// 156.446 us; speedup vs baseline: 5.1697x; 1.0546x over previous
//
#include <hip/hip_runtime.h>
#include <hip/hip_bf16.h>
#include <math.h>
#include <stdint.h>

// Round 4: same 3-kernel split as round 3; GEMM block->tile swizzle now maps
// all 6 n-tiles of each m-panel onto the SAME XCD so the h-panel (A) is
// fetched from HBM/L3 once per XCD instead of 6x across XCDs.

typedef __bf16 bf16_t;
typedef __attribute__((ext_vector_type(8))) __bf16 bf16x8;
typedef __attribute__((ext_vector_type(4))) float f32x4;

#define M_TOT 16384
#define E_DIM 768
#define F_DIM 3072

constexpr int BM = 128, BN = 128, BK = 64;
constexpr int MT = M_TOT / BM;    // 128
constexpr int NT = E_DIM / BN;    // 6
constexpr int KT = F_DIM / BK;    // 48
constexpr int TILE_B = 16384;     // bytes per 128x64 bf16 tile image

// ws layout
constexpr size_t WS_A    = 0;                                    // MT*KT tiles
constexpr size_t WS_B    = WS_A + (size_t)MT * KT * TILE_B;      // NT*KT tiles
constexpr size_t WS_NEED = WS_B + (size_t)NT * KT * TILE_B;      // ~100.5 MiB

// ------------------------------------------------------------ prep: W2 ----
__global__ __launch_bounds__(256)
void ffq_prep_w2t(const float* __restrict__ W2, char* __restrict__ ws)
{
    const int t = threadIdx.x;
    const int kt = blockIdx.x / NT, nt = blockIdx.x % NT;
    __shared__ float Wf[64][132];
    const int r  = t >> 5;
    const int c4 = (t & 31) << 2;
    #pragma unroll
    for (int i = 0; i < 8; ++i) {
        const int row = i * 8 + r;
        const float4 v = *reinterpret_cast<const float4*>(
            &W2[(size_t)(kt * 64 + row) * E_DIM + nt * 128 + c4]);
        Wf[row][c4] = v.x; Wf[row][c4 + 1] = v.y;
        Wf[row][c4 + 2] = v.z; Wf[row][c4 + 3] = v.w;
    }
    __syncthreads();
    char* dst = ws + WS_B + (size_t)(nt * KT + kt) * TILE_B;
    #pragma unroll
    for (int c = 0; c < 4; ++c) {
        const int b16 = c * 256 + t;          // chunk 0..1023
        const int n = b16 >> 3, os = b16 & 7; // stored octet slot
        const int ko = os ^ (n & 7);          // logical k-octet
        bf16x8 v;
        #pragma unroll
        for (int j = 0; j < 8; ++j) v[j] = (bf16_t)Wf[ko * 8 + j][n];
        *reinterpret_cast<bf16x8*>(dst + (size_t)b16 * 16) = v;
    }
}

// ------------------------------------------------------------- prep: h ----
__global__ __launch_bounds__(256)
void ffq_prep_h(const float* __restrict__ x, const float* __restrict__ theta,
                const float* __restrict__ W1, const float* __restrict__ b1,
                char* __restrict__ ws)
{
    __shared__ bf16_t Hsm[BM][BK];
    const int t = threadIdx.x;
    const int mt = blockIdx.x / KT, kt = blockIdx.x % KT;
    const int row = t & 127, half = t >> 7;
    const int m = mt * BM + row;
    const int kb = kt * 64 + half * 32;

    const float4 xv = *reinterpret_cast<const float4*>(x + (size_t)m * E_DIM);
    const float gx = cosf(xv.x) * cosf(theta[0]);
    const float gy = cosf(xv.y) * cosf(theta[1]);
    const float gz = cosf(xv.z) * cosf(theta[2]);
    const float gw = cosf(xv.w) * cosf(theta[3]);

    #pragma unroll
    for (int o = 0; o < 4; ++o) {            // 4 octets of 8 k
        const int k0 = kb + o * 8;
        bf16x8 v;
        #pragma unroll
        for (int j = 0; j < 8; ++j) {
            const int k = k0 + j;
            float p = b1[k];
            p = fmaf(gx, W1[k],              p);
            p = fmaf(gy, W1[F_DIM + k],      p);
            p = fmaf(gz, W1[2 * F_DIM + k],  p);
            p = fmaf(gw, W1[3 * F_DIM + k],  p);
            v[j] = (bf16_t)fmaxf(p, 0.0f);
        }
        const int oc = half * 4 + o;         // logical octet 0..7
        *reinterpret_cast<bf16x8*>(&Hsm[row][(oc ^ (row & 7)) * 8]) = v;
    }
    __syncthreads();
    char* dst = ws + WS_A + (size_t)(mt * KT + kt) * TILE_B;
    const char* srcl = (const char*)&Hsm[0][0];
    #pragma unroll
    for (int r = 0; r < 4; ++r) {
        const int c = r * 256 + t;           // linear chunk copy
        *reinterpret_cast<bf16x8*>(dst + (size_t)c * 16) =
            *reinterpret_cast<const bf16x8*>(srcl + (size_t)c * 16);
    }
}

// ---------------------------------------------------------------- GEMM ----
__global__ __launch_bounds__(256)
void ffq_gemm(const char* __restrict__ ws, const float* __restrict__ b2,
              float* __restrict__ out)
{
    __shared__ bf16_t Asm[BM][BK];   // 16KB, swizzled image (linear copy)
    __shared__ bf16_t Bsm[BN][BK];   // 16KB

    const int t = threadIdx.x;
    const int lane = t & 63, wid = t >> 6;

    // XCD-coherent swizzle: bid&7 ~ XCD (round-robin dispatch). Each XCD gets
    // 16 m-panels x all 6 n-tiles -> A-tile fetched once, L2-hit by 5 peers.
    const int bid = blockIdx.x;                       // 768 = 8 * 96
    const int xcd = bid & 7;
    const int i   = bid >> 3;                         // 0..95
    const int mt  = xcd * 16 + (i & 15);
    const int nt  = i >> 4;                           // 0..5
    const int m0 = mt * BM, n0 = nt * BN;

    const char* srcA = ws + WS_A + (size_t)mt * KT * TILE_B;
    const char* srcB = ws + WS_B + (size_t)nt * KT * TILE_B;

    const int wr = wid >> 1, wc = wid & 1;
    const int fr = lane & 15, fg = lane >> 4;

    f32x4 acc[4][4] = {};

    for (int kt = 0; kt < KT; ++kt) {
        const char* sa = srcA + (size_t)kt * TILE_B;
        const char* sb = srcB + (size_t)kt * TILE_B;
        #pragma unroll
        for (int r = 0; r < 4; ++r) {
            const int off = r * 4096 + wid * 1024 + lane * 16;
            __builtin_amdgcn_global_load_lds(
                (const __attribute__((address_space(1))) void*)(sa + off),
                (__attribute__((address_space(3))) void*)((char*)&Asm[0][0] + r * 4096 + wid * 1024),
                16, 0, 0);
        }
        #pragma unroll
        for (int r = 0; r < 4; ++r) {
            const int off = r * 4096 + wid * 1024 + lane * 16;
            __builtin_amdgcn_global_load_lds(
                (const __attribute__((address_space(1))) void*)(sb + off),
                (__attribute__((address_space(3))) void*)((char*)&Bsm[0][0] + r * 4096 + wid * 1024),
                16, 0, 0);
        }
        __syncthreads();

        #pragma unroll
        for (int ks = 0; ks < 2; ++ks) {
            const int kob = ks * 4 + fg;
            bf16x8 af[4], bfr[4];
            #pragma unroll
            for (int mi = 0; mi < 4; ++mi) {
                const int ra = wr * 64 + mi * 16 + fr;
                af[mi] = *reinterpret_cast<const bf16x8*>(&Asm[ra][(kob ^ (ra & 7)) * 8]);
            }
            #pragma unroll
            for (int ni = 0; ni < 4; ++ni) {
                const int rb = wc * 64 + ni * 16 + fr;
                bfr[ni] = *reinterpret_cast<const bf16x8*>(&Bsm[rb][(kob ^ (rb & 7)) * 8]);
            }
            #pragma unroll
            for (int mi = 0; mi < 4; ++mi)
                #pragma unroll
                for (int ni = 0; ni < 4; ++ni)
                    acc[mi][ni] = __builtin_amdgcn_mfma_f32_16x16x32_bf16(
                        af[mi], bfr[ni], acc[mi][ni], 0, 0, 0);
        }
        __syncthreads();
    }

    #pragma unroll
    for (int ni = 0; ni < 4; ++ni) {
        const int col = n0 + wc * 64 + ni * 16 + fr;
        const float bias = b2[col];
        #pragma unroll
        for (int mi = 0; mi < 4; ++mi) {
            #pragma unroll
            for (int rr = 0; rr < 4; ++rr) {
                const int ro = m0 + wr * 64 + mi * 16 + fg * 4 + rr;
                out[(size_t)ro * E_DIM + col] = acc[mi][ni][rr] + bias;
            }
        }
    }
}

// ------------------------------------------- fallback: round-1 fused ------
__global__ __launch_bounds__(256, 2)
void ffq_fused(const float* __restrict__ x, const float* __restrict__ theta,
               const float* __restrict__ W1, const float* __restrict__ b1,
               const float* __restrict__ W2, const float* __restrict__ b2,
               float* __restrict__ out)
{
    __shared__ bf16_t Asm[BM][BK];
    __shared__ bf16_t Bsm[BN][BK];
    __shared__ float  gsm[BM][4];
    __shared__ float  b2sm[BN];

    const int t = threadIdx.x;
    const int lane = t & 63, wid = t >> 6;
    const int bid = blockIdx.x;
    const int swz = (bid & 7) * (MT * NT / 8) + (bid >> 3);
    const int ntile = swz / MT, mtile = swz % MT;
    const int m0 = mtile * BM, n0 = ntile * BN;

    const float c0 = cosf(theta[0]), c1 = cosf(theta[1]);
    const float c2 = cosf(theta[2]), c3 = cosf(theta[3]);
    if (t < BM) {
        const float4 xv = *reinterpret_cast<const float4*>(x + (size_t)(m0 + t) * E_DIM);
        gsm[t][0] = cosf(xv.x) * c0; gsm[t][1] = cosf(xv.y) * c1;
        gsm[t][2] = cosf(xv.z) * c2; gsm[t][3] = cosf(xv.w) * c3;
    } else {
        const int n = t - 128;
        b2sm[n] = b2[n0 + n];
    }
    __syncthreads();

    const int rg = t >> 3, kg = t & 7;
    const int nB = t & 127, kh = t >> 7;
    const int wr = wid >> 1, wc = wid & 1;
    const int fr = lane & 15, fg = lane >> 4;

    f32x4 acc[4][4] = {};

    for (int k0 = 0; k0 < F_DIM; k0 += BK) {
        {
            const int kA = k0 + (kg << 3);
            float w1v[4][8], b1v[8];
            #pragma unroll
            for (int q = 0; q < 4; ++q) {
                const float4 lo = *reinterpret_cast<const float4*>(&W1[q * F_DIM + kA]);
                const float4 hi = *reinterpret_cast<const float4*>(&W1[q * F_DIM + kA + 4]);
                w1v[q][0] = lo.x; w1v[q][1] = lo.y; w1v[q][2] = lo.z; w1v[q][3] = lo.w;
                w1v[q][4] = hi.x; w1v[q][5] = hi.y; w1v[q][6] = hi.z; w1v[q][7] = hi.w;
            }
            {
                const float4 lo = *reinterpret_cast<const float4*>(&b1[kA]);
                const float4 hi = *reinterpret_cast<const float4*>(&b1[kA + 4]);
                b1v[0] = lo.x; b1v[1] = lo.y; b1v[2] = lo.z; b1v[3] = lo.w;
                b1v[4] = hi.x; b1v[5] = hi.y; b1v[6] = hi.z; b1v[7] = hi.w;
            }
            #pragma unroll
            for (int r = 0; r < 4; ++r) {
                const int row = (rg << 2) + r;
                const float4 g = *reinterpret_cast<const float4*>(&gsm[row][0]);
                bf16x8 v;
                #pragma unroll
                for (int kk = 0; kk < 8; ++kk) {
                    float p = b1v[kk];
                    p = fmaf(g.x, w1v[0][kk], p);
                    p = fmaf(g.y, w1v[1][kk], p);
                    p = fmaf(g.z, w1v[2][kk], p);
                    p = fmaf(g.w, w1v[3][kk], p);
                    v[kk] = (bf16_t)fmaxf(p, 0.0f);
                }
                *reinterpret_cast<bf16x8*>(&Asm[row][(kg ^ (row & 7)) << 3]) = v;
            }
        }
        {
            const float* w2p = W2 + (size_t)(k0 + (kh << 5)) * E_DIM + n0 + nB;
            float bv[32];
            #pragma unroll
            for (int kk = 0; kk < 32; ++kk) bv[kk] = w2p[kk * E_DIM];
            #pragma unroll
            for (int o = 0; o < 4; ++o) {
                bf16x8 v;
                #pragma unroll
                for (int j = 0; j < 8; ++j) v[j] = (bf16_t)bv[(o << 3) + j];
                *reinterpret_cast<bf16x8*>(&Bsm[nB][(((kh << 2) + o) ^ (nB & 7)) << 3]) = v;
            }
        }
        __syncthreads();
        #pragma unroll
        for (int ks = 0; ks < 2; ++ks) {
            const int kob = (ks << 2) + fg;
            bf16x8 af[4], bfr[4];
            #pragma unroll
            for (int mi = 0; mi < 4; ++mi) {
                const int row = (wr << 6) + (mi << 4) + fr;
                af[mi] = *reinterpret_cast<const bf16x8*>(&Asm[row][(kob ^ (row & 7)) << 3]);
            }
            #pragma unroll
            for (int ni = 0; ni < 4; ++ni) {
                const int rn = (wc << 6) + (ni << 4) + fr;
                bfr[ni] = *reinterpret_cast<const bf16x8*>(&Bsm[rn][(kob ^ (rn & 7)) << 3]);
            }
            #pragma unroll
            for (int mi = 0; mi < 4; ++mi)
                #pragma unroll
                for (int ni = 0; ni < 4; ++ni)
                    acc[mi][ni] = __builtin_amdgcn_mfma_f32_16x16x32_bf16(
                        af[mi], bfr[ni], acc[mi][ni], 0, 0, 0);
        }
        __syncthreads();
    }

    #pragma unroll
    for (int mi = 0; mi < 4; ++mi)
        #pragma unroll
        for (int ni = 0; ni < 4; ++ni) {
            const int col  = n0 + (wc << 6) + (ni << 4) + fr;
            const float bias = b2sm[(wc << 6) + (ni << 4) + fr];
            #pragma unroll
            for (int r = 0; r < 4; ++r) {
                const int row = m0 + (wr << 6) + (mi << 4) + (fg << 2) + r;
                out[(size_t)row * E_DIM + col] = acc[mi][ni][r] + bias;
            }
        }
}

// -------------------------------------------------------------- launch ----
extern "C" void kernel_launch(void* const* d_in, const int* in_sizes, int n_in,
                              void* d_out, int out_size, void* d_ws, size_t ws_size,
                              hipStream_t stream) {
    const float* x     = (const float*)d_in[0];
    const float* theta = (const float*)d_in[1];
    const float* W1    = (const float*)d_in[2];
    const float* b1    = (const float*)d_in[3];
    const float* W2    = (const float*)d_in[4];
    const float* b2    = (const float*)d_in[5];
    float* out = (float*)d_out;

    if (ws_size >= WS_NEED) {
        hipLaunchKernelGGL(ffq_prep_w2t, dim3(KT * NT), dim3(256), 0, stream,
                           W2, (char*)d_ws);
        hipLaunchKernelGGL(ffq_prep_h, dim3(MT * KT), dim3(256), 0, stream,
                           x, theta, W1, b1, (char*)d_ws);
        hipLaunchKernelGGL(ffq_gemm, dim3(MT * NT), dim3(256), 0, stream,
                           (const char*)d_ws, b2, out);
    } else {
        hipLaunchKernelGGL(ffq_fused, dim3(MT * NT), dim3(256), 0, stream,
                           x, theta, W1, b1, W2, b2, out);
    }
}

// Round 5
// 117.938 us; speedup vs baseline: 6.8576x; 1.3265x over previous
//
#include <hip/hip_runtime.h>
#include <hip/hip_bf16.h>
#include <math.h>
#include <stdint.h>

// Round 5: double-buffered BK=32 half-tile pipeline (T3/T4 minimum 2-phase).
// STAGE(t+1) issued before compute(t); single __syncthreads per k-step puts
// the vmcnt(0) drain AFTER the MFMA window. LDS = 4 x 8KB = 32KB -> 3 blk/CU.
// ws images: 8KB half-tiles, [row][slot*16] with slot = oc ^ ((row>>1)&3).

typedef __bf16 bf16_t;
typedef __attribute__((ext_vector_type(8))) __bf16 bf16x8;
typedef __attribute__((ext_vector_type(4))) float f32x4;

#define M_TOT 16384
#define E_DIM 768
#define F_DIM 3072

constexpr int BM = 128, BN = 128, BK = 64;
constexpr int MT = M_TOT / BM;    // 128
constexpr int NT = E_DIM / BN;    // 6
constexpr int KT = F_DIM / BK;    // 48
constexpr int KT2 = 2 * KT;       // 96 half-steps (K=32 each)
constexpr int HTILE = 8192;       // bytes per 128x32 bf16 half-tile image

// ws layout (identical byte extents to round 3/4)
constexpr size_t WS_A    = 0;                                    // MT*KT2 half-tiles
constexpr size_t WS_B    = WS_A + (size_t)MT * KT2 * HTILE;
constexpr size_t WS_NEED = WS_B + (size_t)NT * KT2 * HTILE;      // ~100.5 MiB

// ------------------------------------------------------------ prep: W2 ----
__global__ __launch_bounds__(256)
void ffq_prep_w2t(const float* __restrict__ W2, char* __restrict__ ws)
{
    const int t = threadIdx.x;
    const int kt = blockIdx.x / NT, nt = blockIdx.x % NT;
    __shared__ float Wf[64][132];
    const int r  = t >> 5;
    const int c4 = (t & 31) << 2;
    #pragma unroll
    for (int i = 0; i < 8; ++i) {
        const int row = i * 8 + r;
        const float4 v = *reinterpret_cast<const float4*>(
            &W2[(size_t)(kt * 64 + row) * E_DIM + nt * 128 + c4]);
        Wf[row][c4] = v.x; Wf[row][c4 + 1] = v.y;
        Wf[row][c4 + 2] = v.z; Wf[row][c4 + 3] = v.w;
    }
    __syncthreads();
    // two consecutive 8KB half-images: chunk c in 0..1023 of 16B
    char* dst = ws + WS_B + (size_t)(nt * KT + kt) * 2 * HTILE;
    #pragma unroll
    for (int cc = 0; cc < 4; ++cc) {
        const int c    = cc * 256 + t;
        const int half = c >> 9;
        const int q    = c & 511;
        const int n    = q >> 2;
        const int slot = q & 3;
        const int oc   = slot ^ ((n >> 1) & 3);
        bf16x8 v;
        #pragma unroll
        for (int j = 0; j < 8; ++j) v[j] = (bf16_t)Wf[half * 32 + oc * 8 + j][n];
        *reinterpret_cast<bf16x8*>(dst + (size_t)c * 16) = v;
    }
}

// ------------------------------------------------------------- prep: h ----
__global__ __launch_bounds__(256)
void ffq_prep_h(const float* __restrict__ x, const float* __restrict__ theta,
                const float* __restrict__ W1, const float* __restrict__ b1,
                char* __restrict__ ws)
{
    __shared__ __align__(16) char Hsm[16384];   // 2 x 8KB half-images
    const int t = threadIdx.x;
    const int mt = blockIdx.x / KT, kt = blockIdx.x % KT;
    const int row = t & 127, half = t >> 7;
    const int m = mt * BM + row;
    const int kb = kt * 64 + half * 32;

    const float4 xv = *reinterpret_cast<const float4*>(x + (size_t)m * E_DIM);
    const float gx = cosf(xv.x) * cosf(theta[0]);
    const float gy = cosf(xv.y) * cosf(theta[1]);
    const float gz = cosf(xv.z) * cosf(theta[2]);
    const float gw = cosf(xv.w) * cosf(theta[3]);

    #pragma unroll
    for (int o = 0; o < 4; ++o) {            // 4 octets of 8 k within the half
        const int k0 = kb + o * 8;
        bf16x8 v;
        #pragma unroll
        for (int j = 0; j < 8; ++j) {
            const int k = k0 + j;
            float p = b1[k];
            p = fmaf(gx, W1[k],              p);
            p = fmaf(gy, W1[F_DIM + k],      p);
            p = fmaf(gz, W1[2 * F_DIM + k],  p);
            p = fmaf(gw, W1[3 * F_DIM + k],  p);
            v[j] = (bf16_t)fmaxf(p, 0.0f);
        }
        const int slot = o ^ ((row >> 1) & 3);
        *reinterpret_cast<bf16x8*>(&Hsm[half * HTILE + row * 64 + slot * 16]) = v;
    }
    __syncthreads();
    char* dst = ws + WS_A + (size_t)(mt * KT + kt) * 2 * HTILE;
    #pragma unroll
    for (int r = 0; r < 4; ++r) {
        const int c = r * 256 + t;           // linear 16KB copy
        *reinterpret_cast<bf16x8*>(dst + (size_t)c * 16) =
            *reinterpret_cast<const bf16x8*>(&Hsm[c * 16]);
    }
}

// ---------------------------------------------------------------- GEMM ----
__global__ __launch_bounds__(256, 3)
void ffq_gemm(const char* __restrict__ ws, const float* __restrict__ b2,
              float* __restrict__ out)
{
    __shared__ __align__(16) char Ab[2][HTILE];   // 16KB
    __shared__ __align__(16) char Bb[2][HTILE];   // 16KB

    const int t = threadIdx.x;
    const int lane = t & 63, wid = t >> 6;

    // XCD-coherent mapping (round 4, proven): each XCD owns 16 m-panels x 6 nt
    const int bid = blockIdx.x;                       // 768 = 8 * 96
    const int xcd = bid & 7;
    const int i   = bid >> 3;
    const int mt  = xcd * 16 + (i & 15);
    const int nt  = i >> 4;
    const int m0 = mt * BM, n0 = nt * BN;

    const char* srcA = ws + WS_A + (size_t)mt * KT2 * HTILE;
    const char* srcB = ws + WS_B + (size_t)nt * KT2 * HTILE;

    const int wr = wid >> 1, wc = wid & 1;
    const int fr = lane & 15, fg = lane >> 4;

    f32x4 acc[4][4] = {};

    // stage one 8KB A half-tile + one 8KB B half-tile into buffer `buf`
    #define STAGE(kk, buf) do {                                                 \
        const char* sa_ = srcA + (size_t)(kk) * HTILE;                          \
        const char* sb_ = srcB + (size_t)(kk) * HTILE;                          \
        _Pragma("unroll")                                                       \
        for (int r_ = 0; r_ < 2; ++r_) {                                        \
            const int go_ = r_ * 4096 + wid * 1024 + lane * 16;                 \
            const int lo_ = r_ * 4096 + wid * 1024;                             \
            __builtin_amdgcn_global_load_lds(                                   \
                (const __attribute__((address_space(1))) void*)(sa_ + go_),     \
                (__attribute__((address_space(3))) void*)(&Ab[buf][0] + lo_),   \
                16, 0, 0);                                                      \
            __builtin_amdgcn_global_load_lds(                                   \
                (const __attribute__((address_space(1))) void*)(sb_ + go_),     \
                (__attribute__((address_space(3))) void*)(&Bb[buf][0] + lo_),   \
                16, 0, 0);                                                      \
        } } while (0)

    STAGE(0, 0);
    __syncthreads();

    for (int k2 = 0; k2 < KT2; ++k2) {
        const int cur = k2 & 1;
        if (k2 + 1 < KT2) STAGE(k2 + 1, cur ^ 1);   // async; drains at barrier

        bf16x8 af[4], bfr[4];
        #pragma unroll
        for (int mi = 0; mi < 4; ++mi) {
            const int ra = wr * 64 + mi * 16 + fr;
            const int sl = fg ^ ((ra >> 1) & 3);
            af[mi] = *reinterpret_cast<const bf16x8*>(&Ab[cur][ra * 64 + sl * 16]);
        }
        #pragma unroll
        for (int ni = 0; ni < 4; ++ni) {
            const int rb = wc * 64 + ni * 16 + fr;
            const int sl = fg ^ ((rb >> 1) & 3);
            bfr[ni] = *reinterpret_cast<const bf16x8*>(&Bb[cur][rb * 64 + sl * 16]);
        }
        #pragma unroll
        for (int mi = 0; mi < 4; ++mi)
            #pragma unroll
            for (int ni = 0; ni < 4; ++ni)
                acc[mi][ni] = __builtin_amdgcn_mfma_f32_16x16x32_bf16(
                    af[mi], bfr[ni], acc[mi][ni], 0, 0, 0);

        __syncthreads();   // vmcnt(0)+lgkm drain AFTER compute, then barrier
    }
    #undef STAGE

    #pragma unroll
    for (int ni = 0; ni < 4; ++ni) {
        const int col = n0 + wc * 64 + ni * 16 + fr;
        const float bias = b2[col];
        #pragma unroll
        for (int mi = 0; mi < 4; ++mi) {
            #pragma unroll
            for (int rr = 0; rr < 4; ++rr) {
                const int ro = m0 + wr * 64 + mi * 16 + fg * 4 + rr;
                out[(size_t)ro * E_DIM + col] = acc[mi][ni][rr] + bias;
            }
        }
    }
}

// ------------------------------------------- fallback: round-1 fused ------
__global__ __launch_bounds__(256, 2)
void ffq_fused(const float* __restrict__ x, const float* __restrict__ theta,
               const float* __restrict__ W1, const float* __restrict__ b1,
               const float* __restrict__ W2, const float* __restrict__ b2,
               float* __restrict__ out)
{
    __shared__ bf16_t Asm[BM][BK];
    __shared__ bf16_t Bsm[BN][BK];
    __shared__ float  gsm[BM][4];
    __shared__ float  b2sm[BN];

    const int t = threadIdx.x;
    const int lane = t & 63, wid = t >> 6;
    const int bid = blockIdx.x;
    const int swz = (bid & 7) * (MT * NT / 8) + (bid >> 3);
    const int ntile = swz / MT, mtile = swz % MT;
    const int m0 = mtile * BM, n0 = ntile * BN;

    const float c0 = cosf(theta[0]), c1 = cosf(theta[1]);
    const float c2 = cosf(theta[2]), c3 = cosf(theta[3]);
    if (t < BM) {
        const float4 xv = *reinterpret_cast<const float4*>(x + (size_t)(m0 + t) * E_DIM);
        gsm[t][0] = cosf(xv.x) * c0; gsm[t][1] = cosf(xv.y) * c1;
        gsm[t][2] = cosf(xv.z) * c2; gsm[t][3] = cosf(xv.w) * c3;
    } else {
        const int n = t - 128;
        b2sm[n] = b2[n0 + n];
    }
    __syncthreads();

    const int rg = t >> 3, kg = t & 7;
    const int nB = t & 127, kh = t >> 7;
    const int wr = wid >> 1, wc = wid & 1;
    const int fr = lane & 15, fg = lane >> 4;

    f32x4 acc[4][4] = {};

    for (int k0 = 0; k0 < F_DIM; k0 += BK) {
        {
            const int kA = k0 + (kg << 3);
            float w1v[4][8], b1v[8];
            #pragma unroll
            for (int q = 0; q < 4; ++q) {
                const float4 lo = *reinterpret_cast<const float4*>(&W1[q * F_DIM + kA]);
                const float4 hi = *reinterpret_cast<const float4*>(&W1[q * F_DIM + kA + 4]);
                w1v[q][0] = lo.x; w1v[q][1] = lo.y; w1v[q][2] = lo.z; w1v[q][3] = lo.w;
                w1v[q][4] = hi.x; w1v[q][5] = hi.y; w1v[q][6] = hi.z; w1v[q][7] = hi.w;
            }
            {
                const float4 lo = *reinterpret_cast<const float4*>(&b1[kA]);
                const float4 hi = *reinterpret_cast<const float4*>(&b1[kA + 4]);
                b1v[0] = lo.x; b1v[1] = lo.y; b1v[2] = lo.z; b1v[3] = lo.w;
                b1v[4] = hi.x; b1v[5] = hi.y; b1v[6] = hi.z; b1v[7] = hi.w;
            }
            #pragma unroll
            for (int r = 0; r < 4; ++r) {
                const int row = (rg << 2) + r;
                const float4 g = *reinterpret_cast<const float4*>(&gsm[row][0]);
                bf16x8 v;
                #pragma unroll
                for (int kk = 0; kk < 8; ++kk) {
                    float p = b1v[kk];
                    p = fmaf(g.x, w1v[0][kk], p);
                    p = fmaf(g.y, w1v[1][kk], p);
                    p = fmaf(g.z, w1v[2][kk], p);
                    p = fmaf(g.w, w1v[3][kk], p);
                    v[kk] = (bf16_t)fmaxf(p, 0.0f);
                }
                *reinterpret_cast<bf16x8*>(&Asm[row][(kg ^ (row & 7)) << 3]) = v;
            }
        }
        {
            const float* w2p = W2 + (size_t)(k0 + (kh << 5)) * E_DIM + n0 + nB;
            float bv[32];
            #pragma unroll
            for (int kk = 0; kk < 32; ++kk) bv[kk] = w2p[kk * E_DIM];
            #pragma unroll
            for (int o = 0; o < 4; ++o) {
                bf16x8 v;
                #pragma unroll
                for (int j = 0; j < 8; ++j) v[j] = (bf16_t)bv[(o << 3) + j];
                *reinterpret_cast<bf16x8*>(&Bsm[nB][(((kh << 2) + o) ^ (nB & 7)) << 3]) = v;
            }
        }
        __syncthreads();
        #pragma unroll
        for (int ks = 0; ks < 2; ++ks) {
            const int kob = (ks << 2) + fg;
            bf16x8 af[4], bfr[4];
            #pragma unroll
            for (int mi = 0; mi < 4; ++mi) {
                const int row = (wr << 6) + (mi << 4) + fr;
                af[mi] = *reinterpret_cast<const bf16x8*>(&Asm[row][(kob ^ (row & 7)) << 3]);
            }
            #pragma unroll
            for (int ni = 0; ni < 4; ++ni) {
                const int rn = (wc << 6) + (ni << 4) + fr;
                bfr[ni] = *reinterpret_cast<const bf16x8*>(&Bsm[rn][(kob ^ (rn & 7)) << 3]);
            }
            #pragma unroll
            for (int mi = 0; mi < 4; ++mi)
                #pragma unroll
                for (int ni = 0; ni < 4; ++ni)
                    acc[mi][ni] = __builtin_amdgcn_mfma_f32_16x16x32_bf16(
                        af[mi], bfr[ni], acc[mi][ni], 0, 0, 0);
        }
        __syncthreads();
    }

    #pragma unroll
    for (int mi = 0; mi < 4; ++mi)
        #pragma unroll
        for (int ni = 0; ni < 4; ++ni) {
            const int col  = n0 + (wc << 6) + (ni << 4) + fr;
            const float bias = b2sm[(wc << 6) + (ni << 4) + fr];
            #pragma unroll
            for (int r = 0; r < 4; ++r) {
                const int row = m0 + (wr << 6) + (mi << 4) + (fg << 2) + r;
                out[(size_t)row * E_DIM + col] = acc[mi][ni][r] + bias;
            }
        }
}

// -------------------------------------------------------------- launch ----
extern "C" void kernel_launch(void* const* d_in, const int* in_sizes, int n_in,
                              void* d_out, int out_size, void* d_ws, size_t ws_size,
                              hipStream_t stream) {
    const float* x     = (const float*)d_in[0];
    const float* theta = (const float*)d_in[1];
    const float* W1    = (const float*)d_in[2];
    const float* b1    = (const float*)d_in[3];
    const float* W2    = (const float*)d_in[4];
    const float* b2    = (const float*)d_in[5];
    float* out = (float*)d_out;

    if (ws_size >= WS_NEED) {
        hipLaunchKernelGGL(ffq_prep_w2t, dim3(KT * NT), dim3(256), 0, stream,
                           W2, (char*)d_ws);
        hipLaunchKernelGGL(ffq_prep_h, dim3(MT * KT), dim3(256), 0, stream,
                           x, theta, W1, b1, (char*)d_ws);
        hipLaunchKernelGGL(ffq_gemm, dim3(MT * NT), dim3(256), 0, stream,
                           (const char*)d_ws, b2, out);
    } else {
        hipLaunchKernelGGL(ffq_fused, dim3(MT * NT), dim3(256), 0, stream,
                           x, theta, W1, b1, W2, b2, out);
    }
}

// Round 6
// 115.535 us; speedup vs baseline: 7.0003x; 1.0208x over previous
//
#include <hip/hip_runtime.h>
#include <hip/hip_bf16.h>
#include <math.h>
#include <stdint.h>

// Round 6: 3-deep buffer ring + counted vmcnt (T4). Per k-step:
//   s_waitcnt vmcnt(4); s_barrier; sched_barrier; STAGE(k+2); compute(k)
// No vmcnt(0) drain in the main loop. LDS 48KB -> 3 blocks/CU.
// Prep kernels and ws layout identical to round 5.

typedef __bf16 bf16_t;
typedef __attribute__((ext_vector_type(8))) __bf16 bf16x8;
typedef __attribute__((ext_vector_type(4))) float f32x4;

#define M_TOT 16384
#define E_DIM 768
#define F_DIM 3072

constexpr int BM = 128, BN = 128, BK = 64;
constexpr int MT = M_TOT / BM;    // 128
constexpr int NT = E_DIM / BN;    // 6
constexpr int KT = F_DIM / BK;    // 48
constexpr int KT2 = 2 * KT;       // 96 half-steps (K=32 each)
constexpr int HTILE = 8192;       // bytes per 128x32 bf16 half-tile image

// ws layout (identical to round 5)
constexpr size_t WS_A    = 0;                                    // MT*KT2 half-tiles
constexpr size_t WS_B    = WS_A + (size_t)MT * KT2 * HTILE;
constexpr size_t WS_NEED = WS_B + (size_t)NT * KT2 * HTILE;      // ~100.5 MiB

// ------------------------------------------------------------ prep: W2 ----
__global__ __launch_bounds__(256)
void ffq_prep_w2t(const float* __restrict__ W2, char* __restrict__ ws)
{
    const int t = threadIdx.x;
    const int kt = blockIdx.x / NT, nt = blockIdx.x % NT;
    __shared__ float Wf[64][132];
    const int r  = t >> 5;
    const int c4 = (t & 31) << 2;
    #pragma unroll
    for (int i = 0; i < 8; ++i) {
        const int row = i * 8 + r;
        const float4 v = *reinterpret_cast<const float4*>(
            &W2[(size_t)(kt * 64 + row) * E_DIM + nt * 128 + c4]);
        Wf[row][c4] = v.x; Wf[row][c4 + 1] = v.y;
        Wf[row][c4 + 2] = v.z; Wf[row][c4 + 3] = v.w;
    }
    __syncthreads();
    char* dst = ws + WS_B + (size_t)(nt * KT + kt) * 2 * HTILE;
    #pragma unroll
    for (int cc = 0; cc < 4; ++cc) {
        const int c    = cc * 256 + t;
        const int half = c >> 9;
        const int q    = c & 511;
        const int n    = q >> 2;
        const int slot = q & 3;
        const int oc   = slot ^ ((n >> 1) & 3);
        bf16x8 v;
        #pragma unroll
        for (int j = 0; j < 8; ++j) v[j] = (bf16_t)Wf[half * 32 + oc * 8 + j][n];
        *reinterpret_cast<bf16x8*>(dst + (size_t)c * 16) = v;
    }
}

// ------------------------------------------------------------- prep: h ----
__global__ __launch_bounds__(256)
void ffq_prep_h(const float* __restrict__ x, const float* __restrict__ theta,
                const float* __restrict__ W1, const float* __restrict__ b1,
                char* __restrict__ ws)
{
    __shared__ __align__(16) char Hsm[16384];   // 2 x 8KB half-images
    const int t = threadIdx.x;
    const int mt = blockIdx.x / KT, kt = blockIdx.x % KT;
    const int row = t & 127, half = t >> 7;
    const int m = mt * BM + row;
    const int kb = kt * 64 + half * 32;

    const float4 xv = *reinterpret_cast<const float4*>(x + (size_t)m * E_DIM);
    const float gx = cosf(xv.x) * cosf(theta[0]);
    const float gy = cosf(xv.y) * cosf(theta[1]);
    const float gz = cosf(xv.z) * cosf(theta[2]);
    const float gw = cosf(xv.w) * cosf(theta[3]);

    #pragma unroll
    for (int o = 0; o < 4; ++o) {            // 4 octets of 8 k within the half
        const int k0 = kb + o * 8;
        bf16x8 v;
        #pragma unroll
        for (int j = 0; j < 8; ++j) {
            const int k = k0 + j;
            float p = b1[k];
            p = fmaf(gx, W1[k],              p);
            p = fmaf(gy, W1[F_DIM + k],      p);
            p = fmaf(gz, W1[2 * F_DIM + k],  p);
            p = fmaf(gw, W1[3 * F_DIM + k],  p);
            v[j] = (bf16_t)fmaxf(p, 0.0f);
        }
        const int slot = o ^ ((row >> 1) & 3);
        *reinterpret_cast<bf16x8*>(&Hsm[half * HTILE + row * 64 + slot * 16]) = v;
    }
    __syncthreads();
    char* dst = ws + WS_A + (size_t)(mt * KT + kt) * 2 * HTILE;
    #pragma unroll
    for (int r = 0; r < 4; ++r) {
        const int c = r * 256 + t;           // linear 16KB copy
        *reinterpret_cast<bf16x8*>(dst + (size_t)c * 16) =
            *reinterpret_cast<const bf16x8*>(&Hsm[c * 16]);
    }
}

// ---------------------------------------------------------------- GEMM ----
__global__ __launch_bounds__(256, 3)
void ffq_gemm(const char* __restrict__ ws, const float* __restrict__ b2,
              float* __restrict__ out)
{
    __shared__ __align__(16) char Abuf[3][HTILE];   // 24KB
    __shared__ __align__(16) char Bbuf[3][HTILE];   // 24KB

    const int t = threadIdx.x;
    const int lane = t & 63, wid = t >> 6;

    // XCD-coherent mapping: each XCD owns 16 m-panels x all 6 n-tiles
    const int bid = blockIdx.x;                       // 768 = 8 * 96
    const int xcd = bid & 7;
    const int i   = bid >> 3;
    const int mt  = xcd * 16 + (i & 15);
    const int nt  = i >> 4;
    const int m0 = mt * BM, n0 = nt * BN;

    const char* srcA = ws + WS_A + (size_t)mt * KT2 * HTILE;
    const char* srcB = ws + WS_B + (size_t)nt * KT2 * HTILE;

    const int wr = wid >> 1, wc = wid & 1;
    const int fr = lane & 15, fg = lane >> 4;

    f32x4 acc[4][4] = {};

    // one STAGE = exactly 4 global_load_lds per thread (2 A + 2 B)
    #define STAGE(kk, buf) do {                                                 \
        const char* sa_ = srcA + (size_t)(kk) * HTILE;                          \
        const char* sb_ = srcB + (size_t)(kk) * HTILE;                          \
        _Pragma("unroll")                                                       \
        for (int r_ = 0; r_ < 2; ++r_) {                                        \
            const int go_ = r_ * 4096 + wid * 1024 + lane * 16;                 \
            const int lo_ = r_ * 4096 + wid * 1024;                             \
            __builtin_amdgcn_global_load_lds(                                   \
                (const __attribute__((address_space(1))) void*)(sa_ + go_),     \
                (__attribute__((address_space(3))) void*)(&Abuf[buf][0] + lo_), \
                16, 0, 0);                                                      \
            __builtin_amdgcn_global_load_lds(                                   \
                (const __attribute__((address_space(1))) void*)(sb_ + go_),     \
                (__attribute__((address_space(3))) void*)(&Bbuf[buf][0] + lo_), \
                16, 0, 0);                                                      \
        } } while (0)

    #define COMPUTE(buf) do {                                                   \
        const char* ab_ = &Abuf[buf][0];                                        \
        const char* bb_ = &Bbuf[buf][0];                                        \
        bf16x8 af[4], bfr[4];                                                   \
        _Pragma("unroll")                                                       \
        for (int mi = 0; mi < 4; ++mi) {                                        \
            const int ra = wr * 64 + mi * 16 + fr;                              \
            const int sl = fg ^ ((ra >> 1) & 3);                                \
            af[mi] = *reinterpret_cast<const bf16x8*>(ab_ + ra * 64 + sl * 16); \
        }                                                                       \
        _Pragma("unroll")                                                       \
        for (int ni = 0; ni < 4; ++ni) {                                        \
            const int rb = wc * 64 + ni * 16 + fr;                              \
            const int sl = fg ^ ((rb >> 1) & 3);                                \
            bfr[ni] = *reinterpret_cast<const bf16x8*>(bb_ + rb * 64 + sl * 16);\
        }                                                                       \
        __builtin_amdgcn_s_setprio(1);                                          \
        _Pragma("unroll")                                                       \
        for (int mi = 0; mi < 4; ++mi)                                          \
            _Pragma("unroll")                                                   \
            for (int ni = 0; ni < 4; ++ni)                                      \
                acc[mi][ni] = __builtin_amdgcn_mfma_f32_16x16x32_bf16(          \
                    af[mi], bfr[ni], acc[mi][ni], 0, 0, 0);                     \
        __builtin_amdgcn_s_setprio(0);                                          \
    } while (0)

    STAGE(0, 0);
    STAGE(1, 1);

    int buf = 0;
    for (int k2 = 0; k2 < KT2 - 2; ++k2) {
        // tile k2 done (k2+1's 4 loads stay in flight)
        asm volatile("s_waitcnt vmcnt(4)" ::: "memory");
        __builtin_amdgcn_s_barrier();
        __builtin_amdgcn_sched_barrier(0);
        const int nxt = buf + 2 >= 3 ? buf - 1 : buf + 2;   // (buf+2)%3
        STAGE(k2 + 2, nxt);
        COMPUTE(buf);
        buf = buf + 1 >= 3 ? 0 : buf + 1;
    }
    // tail 1: k2 = KT2-2 (tile KT2-1 still in flight)
    asm volatile("s_waitcnt vmcnt(4)" ::: "memory");
    __builtin_amdgcn_s_barrier();
    __builtin_amdgcn_sched_barrier(0);
    COMPUTE(buf);
    buf = buf + 1 >= 3 ? 0 : buf + 1;
    // tail 2: k2 = KT2-1 (drain everything)
    asm volatile("s_waitcnt vmcnt(0)" ::: "memory");
    __builtin_amdgcn_s_barrier();
    __builtin_amdgcn_sched_barrier(0);
    COMPUTE(buf);

    #undef STAGE
    #undef COMPUTE

    #pragma unroll
    for (int ni = 0; ni < 4; ++ni) {
        const int col = n0 + wc * 64 + ni * 16 + fr;
        const float bias = b2[col];
        #pragma unroll
        for (int mi = 0; mi < 4; ++mi) {
            #pragma unroll
            for (int rr = 0; rr < 4; ++rr) {
                const int ro = m0 + wr * 64 + mi * 16 + fg * 4 + rr;
                out[(size_t)ro * E_DIM + col] = acc[mi][ni][rr] + bias;
            }
        }
    }
}

// ------------------------------------------- fallback: round-1 fused ------
__global__ __launch_bounds__(256, 2)
void ffq_fused(const float* __restrict__ x, const float* __restrict__ theta,
               const float* __restrict__ W1, const float* __restrict__ b1,
               const float* __restrict__ W2, const float* __restrict__ b2,
               float* __restrict__ out)
{
    __shared__ bf16_t Asm[BM][BK];
    __shared__ bf16_t Bsm[BN][BK];
    __shared__ float  gsm[BM][4];
    __shared__ float  b2sm[BN];

    const int t = threadIdx.x;
    const int lane = t & 63, wid = t >> 6;
    const int bid = blockIdx.x;
    const int swz = (bid & 7) * (MT * NT / 8) + (bid >> 3);
    const int ntile = swz / MT, mtile = swz % MT;
    const int m0 = mtile * BM, n0 = ntile * BN;

    const float c0 = cosf(theta[0]), c1 = cosf(theta[1]);
    const float c2 = cosf(theta[2]), c3 = cosf(theta[3]);
    if (t < BM) {
        const float4 xv = *reinterpret_cast<const float4*>(x + (size_t)(m0 + t) * E_DIM);
        gsm[t][0] = cosf(xv.x) * c0; gsm[t][1] = cosf(xv.y) * c1;
        gsm[t][2] = cosf(xv.z) * c2; gsm[t][3] = cosf(xv.w) * c3;
    } else {
        const int n = t - 128;
        b2sm[n] = b2[n0 + n];
    }
    __syncthreads();

    const int rg = t >> 3, kg = t & 7;
    const int nB = t & 127, kh = t >> 7;
    const int wr = wid >> 1, wc = wid & 1;
    const int fr = lane & 15, fg = lane >> 4;

    f32x4 acc[4][4] = {};

    for (int k0 = 0; k0 < F_DIM; k0 += BK) {
        {
            const int kA = k0 + (kg << 3);
            float w1v[4][8], b1v[8];
            #pragma unroll
            for (int q = 0; q < 4; ++q) {
                const float4 lo = *reinterpret_cast<const float4*>(&W1[q * F_DIM + kA]);
                const float4 hi = *reinterpret_cast<const float4*>(&W1[q * F_DIM + kA + 4]);
                w1v[q][0] = lo.x; w1v[q][1] = lo.y; w1v[q][2] = lo.z; w1v[q][3] = lo.w;
                w1v[q][4] = hi.x; w1v[q][5] = hi.y; w1v[q][6] = hi.z; w1v[q][7] = hi.w;
            }
            {
                const float4 lo = *reinterpret_cast<const float4*>(&b1[kA]);
                const float4 hi = *reinterpret_cast<const float4*>(&b1[kA + 4]);
                b1v[0] = lo.x; b1v[1] = lo.y; b1v[2] = lo.z; b1v[3] = lo.w;
                b1v[4] = hi.x; b1v[5] = hi.y; b1v[6] = hi.z; b1v[7] = hi.w;
            }
            #pragma unroll
            for (int r = 0; r < 4; ++r) {
                const int row = (rg << 2) + r;
                const float4 g = *reinterpret_cast<const float4*>(&gsm[row][0]);
                bf16x8 v;
                #pragma unroll
                for (int kk = 0; kk < 8; ++kk) {
                    float p = b1v[kk];
                    p = fmaf(g.x, w1v[0][kk], p);
                    p = fmaf(g.y, w1v[1][kk], p);
                    p = fmaf(g.z, w1v[2][kk], p);
                    p = fmaf(g.w, w1v[3][kk], p);
                    v[kk] = (bf16_t)fmaxf(p, 0.0f);
                }
                *reinterpret_cast<bf16x8*>(&Asm[row][(kg ^ (row & 7)) << 3]) = v;
            }
        }
        {
            const float* w2p = W2 + (size_t)(k0 + (kh << 5)) * E_DIM + n0 + nB;
            float bv[32];
            #pragma unroll
            for (int kk = 0; kk < 32; ++kk) bv[kk] = w2p[kk * E_DIM];
            #pragma unroll
            for (int o = 0; o < 4; ++o) {
                bf16x8 v;
                #pragma unroll
                for (int j = 0; j < 8; ++j) v[j] = (bf16_t)bv[(o << 3) + j];
                *reinterpret_cast<bf16x8*>(&Bsm[nB][(((kh << 2) + o) ^ (nB & 7)) << 3]) = v;
            }
        }
        __syncthreads();
        #pragma unroll
        for (int ks = 0; ks < 2; ++ks) {
            const int kob = (ks << 2) + fg;
            bf16x8 af[4], bfr[4];
            #pragma unroll
            for (int mi = 0; mi < 4; ++mi) {
                const int row = (wr << 6) + (mi << 4) + fr;
                af[mi] = *reinterpret_cast<const bf16x8*>(&Asm[row][(kob ^ (row & 7)) << 3]);
            }
            #pragma unroll
            for (int ni = 0; ni < 4; ++ni) {
                const int rn = (wc << 6) + (ni << 4) + fr;
                bfr[ni] = *reinterpret_cast<const bf16x8*>(&Bsm[rn][(kob ^ (rn & 7)) << 3]);
            }
            #pragma unroll
            for (int mi = 0; mi < 4; ++mi)
                #pragma unroll
                for (int ni = 0; ni < 4; ++ni)
                    acc[mi][ni] = __builtin_amdgcn_mfma_f32_16x16x32_bf16(
                        af[mi], bfr[ni], acc[mi][ni], 0, 0, 0);
        }
        __syncthreads();
    }

    #pragma unroll
    for (int mi = 0; mi < 4; ++mi)
        #pragma unroll
        for (int ni = 0; ni < 4; ++ni) {
            const int col  = n0 + (wc << 6) + (ni << 4) + fr;
            const float bias = b2sm[(wc << 6) + (ni << 4) + fr];
            #pragma unroll
            for (int r = 0; r < 4; ++r) {
                const int row = m0 + (wr << 6) + (mi << 4) + (fg << 2) + r;
                out[(size_t)row * E_DIM + col] = acc[mi][ni][r] + bias;
            }
        }
}

// -------------------------------------------------------------- launch ----
extern "C" void kernel_launch(void* const* d_in, const int* in_sizes, int n_in,
                              void* d_out, int out_size, void* d_ws, size_t ws_size,
                              hipStream_t stream) {
    const float* x     = (const float*)d_in[0];
    const float* theta = (const float*)d_in[1];
    const float* W1    = (const float*)d_in[2];
    const float* b1    = (const float*)d_in[3];
    const float* W2    = (const float*)d_in[4];
    const float* b2    = (const float*)d_in[5];
    float* out = (float*)d_out;

    if (ws_size >= WS_NEED) {
        hipLaunchKernelGGL(ffq_prep_w2t, dim3(KT * NT), dim3(256), 0, stream,
                           W2, (char*)d_ws);
        hipLaunchKernelGGL(ffq_prep_h, dim3(MT * KT), dim3(256), 0, stream,
                           x, theta, W1, b1, (char*)d_ws);
        hipLaunchKernelGGL(ffq_gemm, dim3(MT * NT), dim3(256), 0, stream,
                           (const char*)d_ws, b2, out);
    } else {
        hipLaunchKernelGGL(ffq_fused, dim3(MT * NT), dim3(256), 0, stream,
                           x, theta, W1, b1, W2, b2, out);
    }
}